// Round 1
// baseline (1455.635 us; speedup 1.0000x reference)
//
#include <hip/hip_runtime.h>
#include <math.h>

#define N_ROWS 1024
#define DIM    512
#define KQ     65536
#define KNN    200
#define NCLS   1000
#define NBINS  4096
#define CAP    2048
#define INV_T  14.285714285714286f  // 1/0.07

// ---------------------------------------------------------------------------
// Queue circular update: out_qf = queue_features with rows [ptr, ptr+N) set to
// features; out_ql likewise from labels (written as float); out_ptr scalar.
// ---------------------------------------------------------------------------
__global__ __launch_bounds__(256) void update_queue_kernel(
    const float* __restrict__ feats, const float* __restrict__ qf,
    const int* __restrict__ labels, const int* __restrict__ ql,
    const int* __restrict__ qptr,
    float* __restrict__ out_qf, float* __restrict__ out_ql,
    float* __restrict__ out_ptr) {
    int ptr = qptr[0];
    size_t t = (size_t)blockIdx.x * blockDim.x + threadIdx.x;
    size_t total4 = (size_t)KQ * DIM / 4;
    if (t < total4) {
        size_t idx = t * 4;
        int row = (int)(idx >> 9);          // DIM == 512
        int col = (int)(idx & 511);
        int d = row - ptr; if (d < 0) d += KQ;
        float4 v;
        if (d < N_ROWS) v = *(const float4*)(feats + (size_t)d * DIM + col);
        else            v = *(const float4*)(qf + idx);
        *(float4*)(out_qf + idx) = v;
    }
    if (t < KQ) {
        int d = (int)t - ptr; if (d < 0) d += KQ;
        out_ql[t] = (float)((d < N_ROWS) ? labels[d] : ql[t]);
    }
    if (t == 0) out_ptr[0] = (float)((ptr + N_ROWS) % KQ);
}

// ---------------------------------------------------------------------------
// fp32 NT GEMM: C[m,n] = sum_d A[m,d]*B[n,d].  A: [CHx512], B: [65536x512],
// C: [CH x 65536].  64x64 tile, BK=32, 256 threads, 4x4 per thread.
// ---------------------------------------------------------------------------
#define LSTR 68   // LDS k-row stride (64 + 4): keeps float4 alignment, breaks worst write conflicts
#define LA(k, m) ((k) * LSTR + (m))

__global__ __launch_bounds__(256) void gemm_nt_kernel(
    const float* __restrict__ A, const float* __restrict__ B,
    float* __restrict__ C) {
    __shared__ float As[32 * LSTR];
    __shared__ float Bs[32 * LSTR];
    int tid = threadIdx.x;
    int bn = blockIdx.x, bm = blockIdx.y;
    int tx = tid & 15, ty = tid >> 4;
    int lm = tid >> 3;          // 0..31 (loader row)
    int lk = (tid & 7) * 4;     // 0,4,...,28 (loader k)
    const float* Ab = A + (size_t)bm * 64 * DIM;
    const float* Bb = B + (size_t)bn * 64 * DIM;

    float acc[4][4] = {};

    for (int kt = 0; kt < DIM; kt += 32) {
        float4 a0 = *(const float4*)(Ab + (size_t)lm * DIM + kt + lk);
        float4 a1 = *(const float4*)(Ab + (size_t)(lm + 32) * DIM + kt + lk);
        float4 b0 = *(const float4*)(Bb + (size_t)lm * DIM + kt + lk);
        float4 b1 = *(const float4*)(Bb + (size_t)(lm + 32) * DIM + kt + lk);
        __syncthreads();
        As[LA(lk + 0, lm)] = a0.x;  As[LA(lk + 1, lm)] = a0.y;
        As[LA(lk + 2, lm)] = a0.z;  As[LA(lk + 3, lm)] = a0.w;
        As[LA(lk + 0, lm + 32)] = a1.x;  As[LA(lk + 1, lm + 32)] = a1.y;
        As[LA(lk + 2, lm + 32)] = a1.z;  As[LA(lk + 3, lm + 32)] = a1.w;
        Bs[LA(lk + 0, lm)] = b0.x;  Bs[LA(lk + 1, lm)] = b0.y;
        Bs[LA(lk + 2, lm)] = b0.z;  Bs[LA(lk + 3, lm)] = b0.w;
        Bs[LA(lk + 0, lm + 32)] = b1.x;  Bs[LA(lk + 1, lm + 32)] = b1.y;
        Bs[LA(lk + 2, lm + 32)] = b1.z;  Bs[LA(lk + 3, lm + 32)] = b1.w;
        __syncthreads();
#pragma unroll
        for (int kk = 0; kk < 32; ++kk) {
            float4 av = *(const float4*)&As[LA(kk, ty * 4)];
            float4 bv = *(const float4*)&Bs[LA(kk, tx * 4)];
            float a_[4] = {av.x, av.y, av.z, av.w};
            float b_[4] = {bv.x, bv.y, bv.z, bv.w};
#pragma unroll
            for (int i = 0; i < 4; ++i)
#pragma unroll
                for (int j = 0; j < 4; ++j) acc[i][j] += a_[i] * b_[j];
        }
    }
    for (int i = 0; i < 4; ++i) {
        float4 o = make_float4(acc[i][0], acc[i][1], acc[i][2], acc[i][3]);
        *(float4*)(C + (size_t)(bm * 64 + ty * 4 + i) * KQ + bn * 64 + tx * 4) = o;
    }
}

// ---------------------------------------------------------------------------
// Per-row top-200 via 4096-bin radix histogram + exact rank among candidates,
// exp-weighted vote over 1000 classes, argmax, correct-flag write.
// One block (256 threads) per row.
// ---------------------------------------------------------------------------
__device__ __forceinline__ unsigned order_key(float v) {
    unsigned u = __float_as_uint(v);
    return u ^ ((u & 0x80000000u) ? 0xFFFFFFFFu : 0x80000000u);
}

__global__ __launch_bounds__(256) void topk_kernel(
    const float* __restrict__ sim, int r0,
    const int* __restrict__ ql, const int* __restrict__ labels,
    float* __restrict__ flags) {
    __shared__ unsigned hist[NBINS];
    __shared__ unsigned psum[256];
    __shared__ float cval[CAP];
    __shared__ int   cidx[CAP];
    __shared__ float scores[NCLS];
    __shared__ float rbest[256];
    __shared__ int   rcls[256];
    __shared__ int   s_bstar, s_ncand;

    int row = blockIdx.x;
    int tid = threadIdx.x;
    const float4* s4 = (const float4*)(sim + (size_t)row * KQ);

    for (int i = tid; i < NBINS; i += 256) hist[i] = 0;
    if (tid == 0) s_ncand = 0;
    __syncthreads();

    // pass 1: histogram of orderable keys (top 12 bits)
    for (int i4 = tid; i4 < KQ / 4; i4 += 256) {
        float4 v = s4[i4];
        atomicAdd(&hist[order_key(v.x) >> 20], 1u);
        atomicAdd(&hist[order_key(v.y) >> 20], 1u);
        atomicAdd(&hist[order_key(v.z) >> 20], 1u);
        atomicAdd(&hist[order_key(v.w) >> 20], 1u);
    }
    __syncthreads();

    // block suffix-scan to find boundary bin b* (max bin with count(>=b*) >= KNN)
    unsigned loc = 0;
    for (int j = 0; j < 16; ++j) loc += hist[tid * 16 + j];
    psum[tid] = loc;
    __syncthreads();
    for (int off = 1; off < 256; off <<= 1) {
        unsigned add = (tid + off < 256) ? psum[tid + off] : 0u;
        __syncthreads();
        psum[tid] += add;
        __syncthreads();
    }
    unsigned running = psum[tid] - loc;  // count in bins above this thread's chunk
    for (int j = 15; j >= 0; --j) {
        unsigned c = hist[tid * 16 + j];
        if (running < KNN && running + c >= KNN) s_bstar = tid * 16 + j;
        running += c;
    }
    __syncthreads();
    int bstar = s_bstar;

    // pass 2: collect all candidates with bin >= b*
    for (int i4 = tid; i4 < KQ / 4; i4 += 256) {
        float4 v = s4[i4];
        float vv[4] = {v.x, v.y, v.z, v.w};
#pragma unroll
        for (int c = 0; c < 4; ++c) {
            if ((int)(order_key(vv[c]) >> 20) >= bstar) {
                int p = atomicAdd(&s_ncand, 1);
                if (p < CAP) { cval[p] = vv[c]; cidx[p] = i4 * 4 + c; }
            }
        }
    }
    for (int i = tid; i < NCLS; i += 256) scores[i] = 0.f;
    __syncthreads();

    // exact rank among candidates; include if rank < KNN; vote
    int M = s_ncand; if (M > CAP) M = CAP;
    for (int c = tid; c < M; c += 256) {
        float v = cval[c]; int id = cidx[c];
        int rank = 0;
        for (int j = 0; j < M; ++j) {
            float vj = cval[j];
            if (vj > v || (vj == v && cidx[j] < id)) rank++;
        }
        if (rank < KNN) {
            float w = expf(v * INV_T);
            atomicAdd(&scores[ql[id]], w);
        }
    }
    __syncthreads();

    // argmax over classes (ties -> lowest class index)
    float best = -1.f; int bc = 0;
    for (int c = tid; c < NCLS; c += 256) {
        float sc = scores[c];
        if (sc > best) { best = sc; bc = c; }
    }
    rbest[tid] = best; rcls[tid] = bc;
    __syncthreads();
    for (int off = 128; off; off >>= 1) {
        if (tid < off) {
            float ob = rbest[tid + off]; int oc = rcls[tid + off];
            if (ob > rbest[tid] || (ob == rbest[tid] && oc < rcls[tid])) {
                rbest[tid] = ob; rcls[tid] = oc;
            }
        }
        __syncthreads();
    }
    if (tid == 0)
        flags[r0 + row] = (rcls[0] == labels[r0 + row]) ? 1.0f : 0.0f;
}

// ---------------------------------------------------------------------------
// Final accuracy reduction
// ---------------------------------------------------------------------------
__global__ __launch_bounds__(256) void acc_kernel(
    const float* __restrict__ flags, float* __restrict__ out) {
    __shared__ float r[256];
    int tid = threadIdx.x;
    r[tid] = flags[tid] + flags[tid + 256] + flags[tid + 512] + flags[tid + 768];
    __syncthreads();
    for (int off = 128; off; off >>= 1) {
        if (tid < off) r[tid] += r[tid + off];
        __syncthreads();
    }
    if (tid == 0) out[0] = r[0] * (1.0f / 1024.0f);
}

// ---------------------------------------------------------------------------
extern "C" void kernel_launch(void* const* d_in, const int* in_sizes, int n_in,
                              void* d_out, int out_size, void* d_ws, size_t ws_size,
                              hipStream_t stream) {
    const float* feats  = (const float*)d_in[0];
    const float* qf     = (const float*)d_in[1];
    const int*   labels = (const int*)d_in[2];
    const int*   ql     = (const int*)d_in[3];
    const int*   qptr   = (const int*)d_in[4];

    float* out     = (float*)d_out;
    float* out_qf  = out + 1;
    float* out_ql  = out_qf + (size_t)KQ * DIM;
    float* out_ptr = out_ql + KQ;

    // chunked sim buffer in workspace (shrink if ws is small)
    int CH = 256;
    while (CH > 64 &&
           ((size_t)CH * KQ * sizeof(float) + N_ROWS * sizeof(float)) > ws_size)
        CH >>= 1;
    float* sim   = (float*)d_ws;
    float* flags = (float*)((char*)d_ws + (size_t)CH * KQ * sizeof(float));

    {
        int nthreads = 256;
        long long total4 = (long long)KQ * DIM / 4;
        int nblocks = (int)((total4 + nthreads - 1) / nthreads);
        update_queue_kernel<<<nblocks, nthreads, 0, stream>>>(
            feats, qf, labels, ql, qptr, out_qf, out_ql, out_ptr);
    }

    int nchunks = N_ROWS / CH;
    for (int c = 0; c < nchunks; ++c) {
        const float* A = feats + (size_t)c * CH * DIM;
        dim3 g(KQ / 64, CH / 64);
        gemm_nt_kernel<<<g, 256, 0, stream>>>(A, qf, sim);
        topk_kernel<<<CH, 256, 0, stream>>>(sim, c * CH, ql, labels, flags);
    }

    acc_kernel<<<1, 256, 0, stream>>>(flags, out);
}

// Round 2
// 853.396 us; speedup vs baseline: 1.7057x; 1.7057x over previous
//
#include <hip/hip_runtime.h>
#include <math.h>

#define N_ROWS 1024
#define DIM    512
#define KQ     65536
#define KNN    200
#define NCLS   1000
#define NBINS  4096
#define CAP    2048
#define INV_T  14.285714285714286f  // 1/0.07

typedef unsigned short u16;
typedef __attribute__((ext_vector_type(8))) short short8;
typedef __attribute__((ext_vector_type(4))) float f32x4;
struct alignas(8) U16x4 { u16 x, y, z, w; };

// async global->LDS, 16B per lane; LDS dest = wave-uniform base + lane*16
#define GLOAD_LDS16(g, l)                                               \
    __builtin_amdgcn_global_load_lds(                                   \
        (__attribute__((address_space(1))) void*)(g),                   \
        (__attribute__((address_space(3))) void*)(l), 16, 0, 0)

// ---------------------------------------------------------------------------
// Queue circular update
// ---------------------------------------------------------------------------
__global__ __launch_bounds__(256) void update_queue_kernel(
    const float* __restrict__ feats, const float* __restrict__ qf,
    const int* __restrict__ labels, const int* __restrict__ ql,
    const int* __restrict__ qptr,
    float* __restrict__ out_qf, float* __restrict__ out_ql,
    float* __restrict__ out_ptr) {
    int ptr = qptr[0];
    size_t t = (size_t)blockIdx.x * blockDim.x + threadIdx.x;
    size_t total4 = (size_t)KQ * DIM / 4;
    if (t < total4) {
        size_t idx = t * 4;
        int row = (int)(idx >> 9);
        int col = (int)(idx & 511);
        int d = row - ptr; if (d < 0) d += KQ;
        float4 v;
        if (d < N_ROWS) v = *(const float4*)(feats + (size_t)d * DIM + col);
        else            v = *(const float4*)(qf + idx);
        *(float4*)(out_qf + idx) = v;
    }
    if (t < KQ) {
        int d = (int)t - ptr; if (d < 0) d += KQ;
        out_ql[t] = (float)((d < N_ROWS) ? labels[d] : ql[t]);
    }
    if (t == 0) out_ptr[0] = (float)((ptr + N_ROWS) % KQ);
}

// ---------------------------------------------------------------------------
// fp32 -> (hi, lo) bf16 plane split.  x = hi + lo + O(2^-18 x)
// ---------------------------------------------------------------------------
__device__ __forceinline__ void split1(float x, u16& h, u16& l) {
    unsigned u = __float_as_uint(x);
    unsigned hr = (u + 0x7FFFu + ((u >> 16) & 1u)) >> 16;  // RNE to bf16
    float hf = __uint_as_float(hr << 16);
    float lo = x - hf;
    unsigned ul = __float_as_uint(lo);
    unsigned lr = (ul + 0x7FFFu + ((ul >> 16) & 1u)) >> 16;
    h = (u16)hr; l = (u16)lr;
}

__global__ __launch_bounds__(256) void split_kernel(
    const float* __restrict__ X, u16* __restrict__ hi, u16* __restrict__ lo,
    long long n4) {
    long long t = (long long)blockIdx.x * blockDim.x + threadIdx.x;
    if (t >= n4) return;
    float4 v = *(const float4*)(X + t * 4);
    U16x4 h, l;
    split1(v.x, h.x, l.x); split1(v.y, h.y, l.y);
    split1(v.z, h.z, l.z); split1(v.w, h.w, l.w);
    *(U16x4*)(hi + t * 4) = h;
    *(U16x4*)(lo + t * 4) = l;
}

// ---------------------------------------------------------------------------
// bf16-split MFMA NT GEMM: C[m,n] = Ahi.Bhi + Ahi.Blo + Alo.Bhi  (fp32 acc)
// 128x128 tile, BK=32, 256 threads (4 waves, 2x2 of 64x64), m97-style
// global_load_lds staging.  A planes [Mx512], B planes [65536x512], bf16.
// ---------------------------------------------------------------------------
__global__ __launch_bounds__(256, 2) void gemm_mfma_kernel(
    const u16* __restrict__ Ahi, const u16* __restrict__ Alo,
    const u16* __restrict__ Bhi, const u16* __restrict__ Blo,
    float* __restrict__ C) {
    __shared__ u16 sA[2][128 * 32];   // [hi/lo][m][k], k stride 32 (64 B)
    __shared__ u16 sB[2][128 * 32];

    int tid = threadIdx.x;
    int wave = tid >> 6, lane = tid & 63;
    int q = lane >> 4, r = lane & 15;
    int bn = blockIdx.x, bm = blockIdx.y;
    int wm = wave & 1, wn = wave >> 1;

    // staging: wave w stages plane w (Ahi, Alo, Bhi, Blo), 8 units of 16 rows
    const u16* gplane = (wave == 0) ? Ahi : (wave == 1) ? Alo
                      : (wave == 2) ? Bhi : Blo;
    int prow0 = (wave < 2) ? bm * 128 : bn * 128;
    const u16* gbase = gplane + (size_t)prow0 * DIM;
    u16* lbase = (wave == 0) ? sA[0] : (wave == 1) ? sA[1]
               : (wave == 2) ? sB[0] : sB[1];
    int lrow = lane >> 2;      // 0..15 row within 16-row unit
    int lchunk = lane & 3;     // 16B chunk within 64B row

    f32x4 acc[4][4] = {};

    for (int kt = 0; kt < DIM; kt += 32) {
        __syncthreads();
#pragma unroll
        for (int s = 0; s < 8; ++s) {
            const u16* g = gbase + (size_t)(s * 16 + lrow) * DIM + kt + lchunk * 8;
            GLOAD_LDS16(g, lbase + s * 512);
        }
        __syncthreads();

        short8 fa[2][4], fb[2][4];
#pragma unroll
        for (int t = 0; t < 4; ++t) {
            int am = wm * 64 + t * 16 + r;
            fa[0][t] = *(const short8*)&sA[0][am * 32 + q * 8];
            fa[1][t] = *(const short8*)&sA[1][am * 32 + q * 8];
            int bn_ = wn * 64 + t * 16 + r;
            fb[0][t] = *(const short8*)&sB[0][bn_ * 32 + q * 8];
            fb[1][t] = *(const short8*)&sB[1][bn_ * 32 + q * 8];
        }
#pragma unroll
        for (int i = 0; i < 4; ++i)
#pragma unroll
            for (int j = 0; j < 4; ++j) {
                acc[i][j] = __builtin_amdgcn_mfma_f32_16x16x32_bf16(
                    fa[0][i], fb[0][j], acc[i][j], 0, 0, 0);
                acc[i][j] = __builtin_amdgcn_mfma_f32_16x16x32_bf16(
                    fa[0][i], fb[1][j], acc[i][j], 0, 0, 0);
                acc[i][j] = __builtin_amdgcn_mfma_f32_16x16x32_bf16(
                    fa[1][i], fb[0][j], acc[i][j], 0, 0, 0);
            }
    }

    // C/D layout (m89): row = q*4 + reg, col = r  within each 16x16 tile
#pragma unroll
    for (int i = 0; i < 4; ++i)
#pragma unroll
        for (int j = 0; j < 4; ++j)
#pragma unroll
            for (int g = 0; g < 4; ++g) {
                int row = bm * 128 + wm * 64 + i * 16 + q * 4 + g;
                int col = bn * 128 + wn * 64 + j * 16 + r;
                C[(size_t)row * KQ + col] = acc[i][j][g];
            }
}

// ---------------------------------------------------------------------------
// fp32 fallback GEMM (round-1), used only if ws is too small for split planes
// ---------------------------------------------------------------------------
#define LSTR 68
#define LA(k, m) ((k) * LSTR + (m))

__global__ __launch_bounds__(256) void gemm_nt_kernel(
    const float* __restrict__ A, const float* __restrict__ B,
    float* __restrict__ C) {
    __shared__ float As[32 * LSTR];
    __shared__ float Bs[32 * LSTR];
    int tid = threadIdx.x;
    int bn = blockIdx.x, bm = blockIdx.y;
    int tx = tid & 15, ty = tid >> 4;
    int lm = tid >> 3;
    int lk = (tid & 7) * 4;
    const float* Ab = A + (size_t)bm * 64 * DIM;
    const float* Bb = B + (size_t)bn * 64 * DIM;
    float acc[4][4] = {};
    for (int kt = 0; kt < DIM; kt += 32) {
        float4 a0 = *(const float4*)(Ab + (size_t)lm * DIM + kt + lk);
        float4 a1 = *(const float4*)(Ab + (size_t)(lm + 32) * DIM + kt + lk);
        float4 b0 = *(const float4*)(Bb + (size_t)lm * DIM + kt + lk);
        float4 b1 = *(const float4*)(Bb + (size_t)(lm + 32) * DIM + kt + lk);
        __syncthreads();
        As[LA(lk + 0, lm)] = a0.x;  As[LA(lk + 1, lm)] = a0.y;
        As[LA(lk + 2, lm)] = a0.z;  As[LA(lk + 3, lm)] = a0.w;
        As[LA(lk + 0, lm + 32)] = a1.x;  As[LA(lk + 1, lm + 32)] = a1.y;
        As[LA(lk + 2, lm + 32)] = a1.z;  As[LA(lk + 3, lm + 32)] = a1.w;
        Bs[LA(lk + 0, lm)] = b0.x;  Bs[LA(lk + 1, lm)] = b0.y;
        Bs[LA(lk + 2, lm)] = b0.z;  Bs[LA(lk + 3, lm)] = b0.w;
        Bs[LA(lk + 0, lm + 32)] = b1.x;  Bs[LA(lk + 1, lm + 32)] = b1.y;
        Bs[LA(lk + 2, lm + 32)] = b1.z;  Bs[LA(lk + 3, lm + 32)] = b1.w;
        __syncthreads();
#pragma unroll
        for (int kk = 0; kk < 32; ++kk) {
            float4 av = *(const float4*)&As[LA(kk, ty * 4)];
            float4 bv = *(const float4*)&Bs[LA(kk, tx * 4)];
            float a_[4] = {av.x, av.y, av.z, av.w};
            float b_[4] = {bv.x, bv.y, bv.z, bv.w};
#pragma unroll
            for (int i = 0; i < 4; ++i)
#pragma unroll
                for (int j = 0; j < 4; ++j) acc[i][j] += a_[i] * b_[j];
        }
    }
    for (int i = 0; i < 4; ++i) {
        float4 o = make_float4(acc[i][0], acc[i][1], acc[i][2], acc[i][3]);
        *(float4*)(C + (size_t)(bm * 64 + ty * 4 + i) * KQ + bn * 64 + tx * 4) = o;
    }
}

// ---------------------------------------------------------------------------
// Per-row top-200 radix-histogram select + vote + argmax (unchanged, verified)
// ---------------------------------------------------------------------------
__device__ __forceinline__ unsigned order_key(float v) {
    unsigned u = __float_as_uint(v);
    return u ^ ((u & 0x80000000u) ? 0xFFFFFFFFu : 0x80000000u);
}

__global__ __launch_bounds__(256) void topk_kernel(
    const float* __restrict__ sim, int r0,
    const int* __restrict__ ql, const int* __restrict__ labels,
    float* __restrict__ flags) {
    __shared__ unsigned hist[NBINS];
    __shared__ unsigned psum[256];
    __shared__ float cval[CAP];
    __shared__ int   cidx[CAP];
    __shared__ float scores[NCLS];
    __shared__ float rbest[256];
    __shared__ int   rcls[256];
    __shared__ int   s_bstar, s_ncand;

    int row = blockIdx.x;
    int tid = threadIdx.x;
    const float4* s4 = (const float4*)(sim + (size_t)row * KQ);

    for (int i = tid; i < NBINS; i += 256) hist[i] = 0;
    if (tid == 0) s_ncand = 0;
    __syncthreads();

    for (int i4 = tid; i4 < KQ / 4; i4 += 256) {
        float4 v = s4[i4];
        atomicAdd(&hist[order_key(v.x) >> 20], 1u);
        atomicAdd(&hist[order_key(v.y) >> 20], 1u);
        atomicAdd(&hist[order_key(v.z) >> 20], 1u);
        atomicAdd(&hist[order_key(v.w) >> 20], 1u);
    }
    __syncthreads();

    unsigned loc = 0;
    for (int j = 0; j < 16; ++j) loc += hist[tid * 16 + j];
    psum[tid] = loc;
    __syncthreads();
    for (int off = 1; off < 256; off <<= 1) {
        unsigned add = (tid + off < 256) ? psum[tid + off] : 0u;
        __syncthreads();
        psum[tid] += add;
        __syncthreads();
    }
    unsigned running = psum[tid] - loc;
    for (int j = 15; j >= 0; --j) {
        unsigned c = hist[tid * 16 + j];
        if (running < KNN && running + c >= KNN) s_bstar = tid * 16 + j;
        running += c;
    }
    __syncthreads();
    int bstar = s_bstar;

    for (int i4 = tid; i4 < KQ / 4; i4 += 256) {
        float4 v = s4[i4];
        float vv[4] = {v.x, v.y, v.z, v.w};
#pragma unroll
        for (int c = 0; c < 4; ++c) {
            if ((int)(order_key(vv[c]) >> 20) >= bstar) {
                int p = atomicAdd(&s_ncand, 1);
                if (p < CAP) { cval[p] = vv[c]; cidx[p] = i4 * 4 + c; }
            }
        }
    }
    for (int i = tid; i < NCLS; i += 256) scores[i] = 0.f;
    __syncthreads();

    int M = s_ncand; if (M > CAP) M = CAP;
    for (int c = tid; c < M; c += 256) {
        float v = cval[c]; int id = cidx[c];
        int rank = 0;
        for (int j = 0; j < M; ++j) {
            float vj = cval[j];
            if (vj > v || (vj == v && cidx[j] < id)) rank++;
        }
        if (rank < KNN) {
            float w = expf(v * INV_T);
            atomicAdd(&scores[ql[id]], w);
        }
    }
    __syncthreads();

    float best = -1.f; int bc = 0;
    for (int c = tid; c < NCLS; c += 256) {
        float sc = scores[c];
        if (sc > best) { best = sc; bc = c; }
    }
    rbest[tid] = best; rcls[tid] = bc;
    __syncthreads();
    for (int off = 128; off; off >>= 1) {
        if (tid < off) {
            float ob = rbest[tid + off]; int oc = rcls[tid + off];
            if (ob > rbest[tid] || (ob == rbest[tid] && oc < rcls[tid])) {
                rbest[tid] = ob; rcls[tid] = oc;
            }
        }
        __syncthreads();
    }
    if (tid == 0)
        flags[r0 + row] = (rcls[0] == labels[r0 + row]) ? 1.0f : 0.0f;
}

__global__ __launch_bounds__(256) void acc_kernel(
    const float* __restrict__ flags, float* __restrict__ out) {
    __shared__ float r[256];
    int tid = threadIdx.x;
    r[tid] = flags[tid] + flags[tid + 256] + flags[tid + 512] + flags[tid + 768];
    __syncthreads();
    for (int off = 128; off; off >>= 1) {
        if (tid < off) r[tid] += r[tid + off];
        __syncthreads();
    }
    if (tid == 0) out[0] = r[0] * (1.0f / 1024.0f);
}

// ---------------------------------------------------------------------------
extern "C" void kernel_launch(void* const* d_in, const int* in_sizes, int n_in,
                              void* d_out, int out_size, void* d_ws, size_t ws_size,
                              hipStream_t stream) {
    const float* feats  = (const float*)d_in[0];
    const float* qf     = (const float*)d_in[1];
    const int*   labels = (const int*)d_in[2];
    const int*   ql     = (const int*)d_in[3];
    const int*   qptr   = (const int*)d_in[4];

    float* out     = (float*)d_out;
    float* out_qf  = out + 1;
    float* out_ql  = out_qf + (size_t)KQ * DIM;
    float* out_ptr = out_ql + KQ;

    {
        long long total4 = (long long)KQ * DIM / 4;
        int nblocks = (int)((total4 + 255) / 256);
        update_queue_kernel<<<nblocks, 256, 0, stream>>>(
            feats, qf, labels, ql, qptr, out_qf, out_ql, out_ptr);
    }

    const size_t bplane = (size_t)KQ * DIM;       // elements per B plane
    const size_t aplane = (size_t)N_ROWS * DIM;   // elements per A plane

    // pick largest CH for the MFMA path that fits the workspace
    int CH = 0;
    for (int c = 256; c >= 128; c >>= 1) {
        size_t need = 2 * bplane * 2 + 2 * aplane * 2 +
                      (size_t)c * KQ * 4 + N_ROWS * 4;
        if (need <= ws_size) { CH = c; break; }
    }

    if (CH > 0) {
        u16* Bhi = (u16*)d_ws;
        u16* Blo = Bhi + bplane;
        u16* Ahi = Blo + bplane;
        u16* Alo = Ahi + aplane;
        float* sim   = (float*)(Alo + aplane);
        float* flags = sim + (size_t)CH * KQ;

        split_kernel<<<(int)((bplane / 4 + 255) / 256), 256, 0, stream>>>(
            qf, Bhi, Blo, (long long)(bplane / 4));
        split_kernel<<<(int)((aplane / 4 + 255) / 256), 256, 0, stream>>>(
            feats, Ahi, Alo, (long long)(aplane / 4));

        int nchunks = N_ROWS / CH;
        for (int c = 0; c < nchunks; ++c) {
            dim3 g(KQ / 128, CH / 128);
            gemm_mfma_kernel<<<g, 256, 0, stream>>>(
                Ahi + (size_t)c * CH * DIM, Alo + (size_t)c * CH * DIM,
                Bhi, Blo, sim);
            topk_kernel<<<CH, 256, 0, stream>>>(sim, c * CH, ql, labels, flags);
        }
        acc_kernel<<<1, 256, 0, stream>>>(flags, out);
    } else {
        // fp32 fallback (round-1 path)
        int CHf = 256;
        while (CHf > 64 &&
               ((size_t)CHf * KQ * sizeof(float) + N_ROWS * sizeof(float)) > ws_size)
            CHf >>= 1;
        float* sim   = (float*)d_ws;
        float* flags = (float*)((char*)d_ws + (size_t)CHf * KQ * sizeof(float));
        int nchunks = N_ROWS / CHf;
        for (int c = 0; c < nchunks; ++c) {
            const float* A = feats + (size_t)c * CHf * DIM;
            dim3 g(KQ / 64, CHf / 64);
            gemm_nt_kernel<<<g, 256, 0, stream>>>(A, qf, sim);
            topk_kernel<<<CHf, 256, 0, stream>>>(sim, c * CHf, ql, labels, flags);
        }
        acc_kernel<<<1, 256, 0, stream>>>(flags, out);
    }
}

// Round 3
// 677.464 us; speedup vs baseline: 2.1487x; 1.2597x over previous
//
#include <hip/hip_runtime.h>
#include <math.h>

#define N_ROWS 1024
#define DIM    512
#define KQ     65536
#define KNN    200
#define NCLS   1000
#define NBINS  4096
#define CAP    2048
#define INV_T  14.285714285714286f  // 1/0.07

typedef unsigned short u16;
typedef __attribute__((ext_vector_type(8))) short short8;
typedef __attribute__((ext_vector_type(4))) float f32x4;
struct alignas(8) U16x4 { u16 x, y, z, w; };

#define GLOAD_LDS16(g, l)                                               \
    __builtin_amdgcn_global_load_lds(                                   \
        (__attribute__((address_space(1))) void*)(g),                   \
        (__attribute__((address_space(3))) void*)(l), 16, 0, 0)

// ---------------------------------------------------------------------------
// fp32 -> (hi, lo) bf16 split.  x = hi + lo + O(2^-18 x)
// ---------------------------------------------------------------------------
__device__ __forceinline__ void split1(float x, u16& h, u16& l) {
    unsigned u = __float_as_uint(x);
    unsigned hr = (u + 0x7FFFu + ((u >> 16) & 1u)) >> 16;  // RNE to bf16
    float hf = __uint_as_float(hr << 16);
    float lo = x - hf;
    unsigned ul = __float_as_uint(lo);
    unsigned lr = (ul + 0x7FFFu + ((ul >> 16) & 1u)) >> 16;
    h = (u16)hr; l = (u16)lr;
}

// ---------------------------------------------------------------------------
// Fused: queue circular update + bf16 plane split of B (=old qf) and A (=feats)
// Blocks [0, 32768): one quad of qf per thread.
// Blocks [32768, 33280): one quad of feats per thread (A split).
// ---------------------------------------------------------------------------
#define QF_BLOCKS (KQ * DIM / 4 / 256)        // 32768
#define FT_BLOCKS (N_ROWS * DIM / 4 / 256)    // 512

__global__ __launch_bounds__(256) void fused_update_split_kernel(
    const float* __restrict__ feats, const float* __restrict__ qf,
    const int* __restrict__ labels, const int* __restrict__ ql,
    const int* __restrict__ qptr,
    float* __restrict__ out_qf, float* __restrict__ out_ql,
    float* __restrict__ out_ptr,
    u16* __restrict__ Bhi, u16* __restrict__ Blo,
    u16* __restrict__ Ahi, u16* __restrict__ Alo) {
    int ptr = qptr[0];
    int b = blockIdx.x;
    if (b < QF_BLOCKS) {
        size_t t = (size_t)b * 256 + threadIdx.x;   // quad index into qf
        size_t idx = t * 4;
        int row = (int)(idx >> 9);
        int col = (int)(idx & 511);
        float4 v = *(const float4*)(qf + idx);
        // B plane split (from ORIGINAL queue)
        U16x4 h, l;
        split1(v.x, h.x, l.x); split1(v.y, h.y, l.y);
        split1(v.z, h.z, l.z); split1(v.w, h.w, l.w);
        *(U16x4*)(Bhi + idx) = h;
        *(U16x4*)(Blo + idx) = l;
        // circular queue feature update
        int d = row - ptr; if (d < 0) d += KQ;
        float4 o = (d < N_ROWS) ? *(const float4*)(feats + (size_t)d * DIM + col) : v;
        *(float4*)(out_qf + idx) = o;
        // labels (one lane per row)
        if (col == 0)
            out_ql[row] = (float)((d < N_ROWS) ? labels[d] : ql[row]);
    } else {
        size_t t = (size_t)(b - QF_BLOCKS) * 256 + threadIdx.x;  // quad in feats
        size_t idx = t * 4;
        float4 v = *(const float4*)(feats + idx);
        U16x4 h, l;
        split1(v.x, h.x, l.x); split1(v.y, h.y, l.y);
        split1(v.z, h.z, l.z); split1(v.w, h.w, l.w);
        *(U16x4*)(Ahi + idx) = h;
        *(U16x4*)(Alo + idx) = l;
        if (t == 0) out_ptr[0] = (float)((ptr + N_ROWS) % KQ);
    }
}

// ---------------------------------------------------------------------------
// bf16-split MFMA NT GEMM: C = Ahi.Bhi + Ahi.Blo + Alo.Bhi  (fp32 acc)
// 128x128 tile, BK=32, 256 threads (2x2 waves of 64x64)
// ---------------------------------------------------------------------------
__global__ __launch_bounds__(256, 4) void gemm_mfma_kernel(
    const u16* __restrict__ Ahi, const u16* __restrict__ Alo,
    const u16* __restrict__ Bhi, const u16* __restrict__ Blo,
    float* __restrict__ C) {
    __shared__ u16 sA[2][128 * 32];   // [hi/lo][m][k]
    __shared__ u16 sB[2][128 * 32];

    int tid = threadIdx.x;
    int wave = tid >> 6, lane = tid & 63;
    int q = lane >> 4, r = lane & 15;
    int bn = blockIdx.x, bm = blockIdx.y;
    int wm = wave & 1, wn = wave >> 1;

    const u16* gplane = (wave == 0) ? Ahi : (wave == 1) ? Alo
                      : (wave == 2) ? Bhi : Blo;
    int prow0 = (wave < 2) ? bm * 128 : bn * 128;
    const u16* gbase = gplane + (size_t)prow0 * DIM;
    u16* lbase = (wave == 0) ? sA[0] : (wave == 1) ? sA[1]
               : (wave == 2) ? sB[0] : sB[1];
    int lrow = lane >> 2;
    int lchunk = lane & 3;

    f32x4 acc[4][4] = {};

    for (int kt = 0; kt < DIM; kt += 32) {
        __syncthreads();
#pragma unroll
        for (int s = 0; s < 8; ++s) {
            const u16* g = gbase + (size_t)(s * 16 + lrow) * DIM + kt + lchunk * 8;
            GLOAD_LDS16(g, lbase + s * 512);
        }
        __syncthreads();

        short8 fa[2][4], fb[2][4];
#pragma unroll
        for (int t = 0; t < 4; ++t) {
            int am = wm * 64 + t * 16 + r;
            fa[0][t] = *(const short8*)&sA[0][am * 32 + q * 8];
            fa[1][t] = *(const short8*)&sA[1][am * 32 + q * 8];
            int bn_ = wn * 64 + t * 16 + r;
            fb[0][t] = *(const short8*)&sB[0][bn_ * 32 + q * 8];
            fb[1][t] = *(const short8*)&sB[1][bn_ * 32 + q * 8];
        }
#pragma unroll
        for (int i = 0; i < 4; ++i)
#pragma unroll
            for (int j = 0; j < 4; ++j) {
                acc[i][j] = __builtin_amdgcn_mfma_f32_16x16x32_bf16(
                    fa[0][i], fb[0][j], acc[i][j], 0, 0, 0);
                acc[i][j] = __builtin_amdgcn_mfma_f32_16x16x32_bf16(
                    fa[0][i], fb[1][j], acc[i][j], 0, 0, 0);
                acc[i][j] = __builtin_amdgcn_mfma_f32_16x16x32_bf16(
                    fa[1][i], fb[0][j], acc[i][j], 0, 0, 0);
            }
    }

#pragma unroll
    for (int i = 0; i < 4; ++i)
#pragma unroll
        for (int j = 0; j < 4; ++j)
#pragma unroll
            for (int g = 0; g < 4; ++g) {
                int row = bm * 128 + wm * 64 + i * 16 + q * 4 + g;
                int col = bn * 128 + wn * 64 + j * 16 + r;
                C[(size_t)row * KQ + col] = acc[i][j][g];
            }
}

// ---------------------------------------------------------------------------
// fp32 fallback GEMM (only if ws too small for planes)
// ---------------------------------------------------------------------------
#define LSTR 68
#define LA(k, m) ((k) * LSTR + (m))

__global__ __launch_bounds__(256) void gemm_nt_kernel(
    const float* __restrict__ A, const float* __restrict__ B,
    float* __restrict__ C) {
    __shared__ float As[32 * LSTR];
    __shared__ float Bs[32 * LSTR];
    int tid = threadIdx.x;
    int bn = blockIdx.x, bm = blockIdx.y;
    int tx = tid & 15, ty = tid >> 4;
    int lm = tid >> 3;
    int lk = (tid & 7) * 4;
    const float* Ab = A + (size_t)bm * 64 * DIM;
    const float* Bb = B + (size_t)bn * 64 * DIM;
    float acc[4][4] = {};
    for (int kt = 0; kt < DIM; kt += 32) {
        float4 a0 = *(const float4*)(Ab + (size_t)lm * DIM + kt + lk);
        float4 a1 = *(const float4*)(Ab + (size_t)(lm + 32) * DIM + kt + lk);
        float4 b0 = *(const float4*)(Bb + (size_t)lm * DIM + kt + lk);
        float4 b1 = *(const float4*)(Bb + (size_t)(lm + 32) * DIM + kt + lk);
        __syncthreads();
        As[LA(lk + 0, lm)] = a0.x;  As[LA(lk + 1, lm)] = a0.y;
        As[LA(lk + 2, lm)] = a0.z;  As[LA(lk + 3, lm)] = a0.w;
        As[LA(lk + 0, lm + 32)] = a1.x;  As[LA(lk + 1, lm + 32)] = a1.y;
        As[LA(lk + 2, lm + 32)] = a1.z;  As[LA(lk + 3, lm + 32)] = a1.w;
        Bs[LA(lk + 0, lm)] = b0.x;  Bs[LA(lk + 1, lm)] = b0.y;
        Bs[LA(lk + 2, lm)] = b0.z;  Bs[LA(lk + 3, lm)] = b0.w;
        Bs[LA(lk + 0, lm + 32)] = b1.x;  Bs[LA(lk + 1, lm + 32)] = b1.y;
        Bs[LA(lk + 2, lm + 32)] = b1.z;  Bs[LA(lk + 3, lm + 32)] = b1.w;
        __syncthreads();
#pragma unroll
        for (int kk = 0; kk < 32; ++kk) {
            float4 av = *(const float4*)&As[LA(kk, ty * 4)];
            float4 bv = *(const float4*)&Bs[LA(kk, tx * 4)];
            float a_[4] = {av.x, av.y, av.z, av.w};
            float b_[4] = {bv.x, bv.y, bv.z, bv.w};
#pragma unroll
            for (int i = 0; i < 4; ++i)
#pragma unroll
                for (int j = 0; j < 4; ++j) acc[i][j] += a_[i] * b_[j];
        }
    }
    for (int i = 0; i < 4; ++i) {
        float4 o = make_float4(acc[i][0], acc[i][1], acc[i][2], acc[i][3]);
        *(float4*)(C + (size_t)(bm * 64 + ty * 4 + i) * KQ + bn * 64 + tx * 4) = o;
    }
}

// ---------------------------------------------------------------------------
// Per-row top-200: 1024 threads/block (16 waves -> real latency hiding).
// Radix histogram (4096 bins) + exact rank among candidates + vote + argmax.
// ---------------------------------------------------------------------------
__device__ __forceinline__ unsigned order_key(float v) {
    unsigned u = __float_as_uint(v);
    return u ^ ((u & 0x80000000u) ? 0xFFFFFFFFu : 0x80000000u);
}

__global__ __launch_bounds__(1024) void topk_kernel(
    const float* __restrict__ sim, int r0,
    const int* __restrict__ ql, const int* __restrict__ labels,
    float* __restrict__ flags) {
    __shared__ unsigned hist[NBINS];
    __shared__ unsigned psum[1024];
    __shared__ float cval[CAP];
    __shared__ int   cidx[CAP];
    __shared__ float scores[NCLS];
    __shared__ float rbest[1024];
    __shared__ int   rcls[1024];
    __shared__ int   s_bstar, s_ncand;

    int row = blockIdx.x;
    int tid = threadIdx.x;
    const float4* s4 = (const float4*)(sim + (size_t)row * KQ);

    hist[tid] = 0; hist[tid + 1024] = 0; hist[tid + 2048] = 0; hist[tid + 3072] = 0;
    if (tid == 0) s_ncand = 0;
    __syncthreads();

    // pass 1: 12-bit histogram (16 float4 iters per thread)
    for (int i4 = tid; i4 < KQ / 4; i4 += 1024) {
        float4 v = s4[i4];
        atomicAdd(&hist[order_key(v.x) >> 20], 1u);
        atomicAdd(&hist[order_key(v.y) >> 20], 1u);
        atomicAdd(&hist[order_key(v.z) >> 20], 1u);
        atomicAdd(&hist[order_key(v.w) >> 20], 1u);
    }
    __syncthreads();

    // suffix-scan: thread t owns bins [4t, 4t+4)
    unsigned loc = hist[4 * tid] + hist[4 * tid + 1] +
                   hist[4 * tid + 2] + hist[4 * tid + 3];
    psum[tid] = loc;
    __syncthreads();
    for (int off = 1; off < 1024; off <<= 1) {
        unsigned add = (tid + off < 1024) ? psum[tid + off] : 0u;
        __syncthreads();
        psum[tid] += add;
        __syncthreads();
    }
    unsigned running = psum[tid] - loc;   // count above this thread's chunk
    for (int j = 3; j >= 0; --j) {
        unsigned c = hist[4 * tid + j];
        if (running < KNN && running + c >= KNN) s_bstar = 4 * tid + j;
        running += c;
    }
    __syncthreads();
    int bstar = s_bstar;

    // pass 2: collect candidates with bin >= b*
    for (int i4 = tid; i4 < KQ / 4; i4 += 1024) {
        float4 v = s4[i4];
        float vv[4] = {v.x, v.y, v.z, v.w};
#pragma unroll
        for (int c = 0; c < 4; ++c) {
            if ((int)(order_key(vv[c]) >> 20) >= bstar) {
                int p = atomicAdd(&s_ncand, 1);
                if (p < CAP) { cval[p] = vv[c]; cidx[p] = i4 * 4 + c; }
            }
        }
    }
    if (tid < NCLS) scores[tid] = 0.f;
    __syncthreads();

    // exact rank among candidates; vote
    int M = s_ncand; if (M > CAP) M = CAP;
    for (int c = tid; c < M; c += 1024) {
        float v = cval[c]; int id = cidx[c];
        int rank = 0;
        for (int j = 0; j < M; ++j) {
            float vj = cval[j];
            if (vj > v || (vj == v && cidx[j] < id)) rank++;
        }
        if (rank < KNN) {
            float w = expf(v * INV_T);
            atomicAdd(&scores[ql[id]], w);
        }
    }
    __syncthreads();

    // argmax over classes (ties -> lowest class index)
    float best = -1.f; int bc = 0;
    if (tid < NCLS) { best = scores[tid]; bc = tid; }
    rbest[tid] = best; rcls[tid] = bc;
    __syncthreads();
    for (int off = 512; off; off >>= 1) {
        if (tid < off) {
            float ob = rbest[tid + off]; int oc = rcls[tid + off];
            if (ob > rbest[tid] || (ob == rbest[tid] && oc < rcls[tid])) {
                rbest[tid] = ob; rcls[tid] = oc;
            }
        }
        __syncthreads();
    }
    if (tid == 0)
        flags[r0 + row] = (rcls[0] == labels[r0 + row]) ? 1.0f : 0.0f;
}

__global__ __launch_bounds__(256) void acc_kernel(
    const float* __restrict__ flags, float* __restrict__ out) {
    __shared__ float r[256];
    int tid = threadIdx.x;
    r[tid] = flags[tid] + flags[tid + 256] + flags[tid + 512] + flags[tid + 768];
    __syncthreads();
    for (int off = 128; off; off >>= 1) {
        if (tid < off) r[tid] += r[tid + off];
        __syncthreads();
    }
    if (tid == 0) out[0] = r[0] * (1.0f / 1024.0f);
}

// ---------------------------------------------------------------------------
extern "C" void kernel_launch(void* const* d_in, const int* in_sizes, int n_in,
                              void* d_out, int out_size, void* d_ws, size_t ws_size,
                              hipStream_t stream) {
    const float* feats  = (const float*)d_in[0];
    const float* qf     = (const float*)d_in[1];
    const int*   labels = (const int*)d_in[2];
    const int*   ql     = (const int*)d_in[3];
    const int*   qptr   = (const int*)d_in[4];

    float* out     = (float*)d_out;
    float* out_qf  = out + 1;
    float* out_ql  = out_qf + (size_t)KQ * DIM;
    float* out_ptr = out_ql + KQ;

    const size_t bplane = (size_t)KQ * DIM;
    const size_t aplane = (size_t)N_ROWS * DIM;

    int CH = 0;
    for (int c = 256; c >= 128; c >>= 1) {
        size_t need = 2 * bplane * 2 + 2 * aplane * 2 +
                      (size_t)c * KQ * 4 + N_ROWS * 4;
        if (need <= ws_size) { CH = c; break; }
    }

    if (CH > 0) {
        u16* Bhi = (u16*)d_ws;
        u16* Blo = Bhi + bplane;
        u16* Ahi = Blo + bplane;
        u16* Alo = Ahi + aplane;
        float* sim   = (float*)(Alo + aplane);
        float* flags = sim + (size_t)CH * KQ;

        fused_update_split_kernel<<<QF_BLOCKS + FT_BLOCKS, 256, 0, stream>>>(
            feats, qf, labels, ql, qptr, out_qf, out_ql, out_ptr,
            Bhi, Blo, Ahi, Alo);

        int nchunks = N_ROWS / CH;
        for (int c = 0; c < nchunks; ++c) {
            dim3 g(KQ / 128, CH / 128);
            gemm_mfma_kernel<<<g, 256, 0, stream>>>(
                Ahi + (size_t)c * CH * DIM, Alo + (size_t)c * CH * DIM,
                Bhi, Blo, sim);
            topk_kernel<<<CH, 1024, 0, stream>>>(sim, c * CH, ql, labels, flags);
        }
        acc_kernel<<<1, 256, 0, stream>>>(flags, out);
    } else {
        // fp32 fallback path
        {
            long long total4 = (long long)KQ * DIM / 4;
            // minimal separate queue update (reuse fused kernel shape is overkill)
            // fall back to chunked fp32 GEMM + topk
        }
        // queue update via fused kernel with dummy plane targets is not possible
        // without ws; do a simple update inline here using the fp32 GEMM's ws.
        int CHf = 256;
        while (CHf > 64 &&
               ((size_t)CHf * KQ * sizeof(float) + N_ROWS * sizeof(float)) > ws_size)
            CHf >>= 1;
        float* sim   = (float*)d_ws;
        float* flags = (float*)((char*)d_ws + (size_t)CHf * KQ * sizeof(float));
        // queue update (no split): reuse fused kernel with B/A planes pointed at
        // sim scratch (harmless, overwritten by GEMM afterwards).
        fused_update_split_kernel<<<QF_BLOCKS + FT_BLOCKS, 256, 0, stream>>>(
            feats, qf, labels, ql, qptr, out_qf, out_ql, out_ptr,
            (u16*)sim, (u16*)sim, (u16*)sim, (u16*)sim);
        int nchunks = N_ROWS / CHf;
        for (int c = 0; c < nchunks; ++c) {
            const float* A = feats + (size_t)c * CHf * DIM;
            dim3 g(KQ / 64, CHf / 64);
            gemm_nt_kernel<<<g, 256, 0, stream>>>(A, qf, sim);
            topk_kernel<<<CHf, 1024, 0, stream>>>(sim, c * CHf, ql, labels, flags);
        }
        acc_kernel<<<1, 256, 0, stream>>>(flags, out);
    }
}